// Round 5
// baseline (676.006 us; speedup 1.0000x reference)
//
#include <hip/hip_runtime.h>
#include <hip/hip_bf16.h>

#define NB    8192
#define DICT  14
#define SE    32
#define CC    64
#define EDIM  256
#define NZV   512
#define C1N   16
#define C2N   32

typedef __attribute__((ext_vector_type(8))) short bf16x8;
typedef __attribute__((ext_vector_type(4))) float f32x4;

// split fp32 -> bf16 hi (truncate) + bf16 lo (RNE of residual); 3-term MFMA
__device__ __forceinline__ void split_hl(float x, unsigned short& h, unsigned short& l) {
    unsigned u = __float_as_uint(x);
    unsigned short hh = (unsigned short)(u >> 16);
    float hf = __uint_as_float((unsigned)hh << 16);
    float lof = x - hf;
    unsigned ul = __float_as_uint(lof);
    l = (unsigned short)((ul + 0x7FFFu + ((ul >> 16) & 1u)) >> 16);
    h = hh;
}

// ---------------- prep: normalize embedding rows (max_norm=1) --------------
__global__ __launch_bounds__(64) void k_norm_embed(const float* __restrict__ tab,
                                                   float* __restrict__ tn) {
    int d = blockIdx.x, l = threadIdx.x;
    float v = (l < SE) ? tab[d * SE + l] : 0.f;
    float s = v * v;
    #pragma unroll
    for (int o = 32; o > 0; o >>= 1) s += __shfl_down(s, o, 64);
    s = __shfl(s, 0, 64);
    float sc = fminf(1.f, 1.f / (sqrtf(s) + 1e-7f));
    if (l < SE) tn[d * SE + l] = v * sc;
}

// ---- norm z (h/l bf16) + split linear weights, one launch -----------------
__global__ __launch_bounds__(256) void k_prep_zw(const float* __restrict__ z,
        const float* __restrict__ lwa, const float* __restrict__ lwb,
        unsigned short* __restrict__ znh, unsigned short* __restrict__ znl,
        unsigned short* __restrict__ wh, unsigned short* __restrict__ wl) {
    int bid = blockIdx.x, t = threadIdx.x;
    if (bid < NZV) {
        __shared__ float red[4];
        float v = z[bid * EDIM + t];
        float s = v * v;
        #pragma unroll
        for (int o = 32; o > 0; o >>= 1) s += __shfl_down(s, o, 64);
        if ((t & 63) == 0) red[t >> 6] = s;
        __syncthreads();
        float tot = red[0] + red[1] + red[2] + red[3];
        float nv = v / sqrtf(tot);
        unsigned short h, l;
        split_hl(nv, h, l);
        znh[bid * EDIM + t] = h;
        znl[bid * EDIM + t] = l;
    } else {
        int i = (bid - NZV) * 256 + t;            // [2][256][800]
        if (i < 2 * EDIM * 800) {
            float v = (i < EDIM * 800) ? lwa[i] : lwb[i - EDIM * 800];
            unsigned short h, l;
            split_hl(v, h, l);
            wh[i] = h; wl[i] = l;
        }
    }
}

// ---- build_A + build_beff merged ------------------------------------------
__global__ __launch_bounds__(256) void k_prep_ab(const float* __restrict__ we,
        const float* __restrict__ tn,
        const float* __restrict__ w1a, const float* __restrict__ b1a,
        const float* __restrict__ w1b, const float* __restrict__ b1b,
        const float* __restrict__ be,
        float* __restrict__ A, float* __restrict__ beff) {
    if (blockIdx.x < 32) {
        int i = blockIdx.x * 256 + threadIdx.x;
        if (i >= DICT * CC * 9) return;
        int f = i % 9, c1 = (i / 9) % CC, d = i / (9 * CC);
        float acc = 0.f;
        #pragma unroll
        for (int c0 = 0; c0 < SE; c0++) acc += we[(c1 * SE + c0) * 9 + f] * tn[d * SE + c0];
        A[i] = acc;
    } else {
        int t = blockIdx.x - 32;
        const float* w1 = t ? w1b : w1a;
        const float* b1 = t ? b1b : b1a;
        for (int j = threadIdx.x; j < 400; j += blockDim.x) {
            int o = j / 25, y = (j / 5) % 5, x = j % 5;
            float acc = b1[o];
            if (t == 0) {
                for (int ey = 0; ey < 3; ey++) {
                    int py = y + ey - 1; if (py < 0 || py > 4) continue;
                    for (int ex = 0; ex < 3; ex++) {
                        int px = x + ex - 1; if (px < 0 || px > 4) continue;
                        for (int c1 = 0; c1 < CC; c1++)
                            acc += w1[((o * CC + c1) * 3 + ey) * 3 + ex] * be[c1];
                    }
                }
            }
            beff[t * 400 + j] = acc;
        }
    }
}

// ---- T[t][q][d][j] = composed conv1(conv_embed(onehot)) table -------------
__global__ __launch_bounds__(256) void k_build_T(const float* __restrict__ w1a,
                                                 const float* __restrict__ w1b,
                                                 const float* __restrict__ A,
                                                 float* __restrict__ T) {
    int t = blockIdx.y;
    int qd = blockIdx.x;
    int d = qd % DICT, q = qd / DICT;
    int qy = q / 5, qx = q % 5;
    const float* w1 = t ? w1b : w1a;
    __shared__ float w1s[C1N * CC * 9];
    __shared__ float As[CC * 9];
    for (int i = threadIdx.x; i < C1N * CC * 9; i += 256) w1s[i] = w1[i];
    for (int i = threadIdx.x; i < CC * 9; i += 256) As[i] = A[d * CC * 9 + i];
    __syncthreads();
    float* Tout = T + (((size_t)t * 25 + q) * DICT + d) * 400;
    for (int j = threadIdx.x; j < 400; j += 256) {
        int o = j / 25, y = (j / 5) % 5, x = j % 5;
        float acc = 0.f;
        int py0 = max(0, max(y - 1, qy - 1)), py1 = min(4, min(y + 1, qy + 1));
        int px0 = max(0, max(x - 1, qx - 1)), px1 = min(4, min(x + 1, qx + 1));
        for (int py = py0; py <= py1; py++)
            for (int px = px0; px <= px1; px++) {
                int ey = py - y + 1, ex = px - x + 1;
                int fy = qy - py + 1, fx = qx - px + 1;
                const float* wp = &w1s[(o * CC) * 9 + (ey * 3 + ex)];
                const float* ap = &As[fy * 3 + fx];
                float pa = 0.f;
                #pragma unroll 8
                for (int c1 = 0; c1 < CC; c1++) pa += wp[c1 * 9] * ap[c1 * 9];
                acc += pa;
            }
        Tout[j] = acc;
    }
}

// conv2 pixel-quarter body: compile-time pixel range [P0,P1)
template<int P0, int P1>
__device__ __forceinline__ void conv2_body(const float* __restrict__ a1row,
                                           const float* __restrict__ w2,
                                           int o2, float bias2,
                                           unsigned short* __restrict__ a2h,
                                           unsigned short* __restrict__ a2l,
                                           int kbase) {
    constexpr int NP = P1 - P0;
    float cacc[NP];
    #pragma unroll
    for (int i = 0; i < NP; i++) cacc[i] = bias2;
    for (int c1 = 0; c1 < C1N; c1++) {
        const float* rp = a1row + c1 * 28;
        float row[25];
        #pragma unroll
        for (int v = 0; v < 6; v++) *(float4*)&row[v * 4] = *(const float4*)&rp[v * 4];
        row[24] = rp[24];
        const float* wp = &w2[(o2 * C1N + c1) * 9];
        #pragma unroll
        for (int ky = 0; ky < 3; ky++)
        #pragma unroll
        for (int kx = 0; kx < 3; kx++) {
            float w = wp[ky * 3 + kx];
            #pragma unroll
            for (int i = 0; i < NP; i++) {
                int p = P0 + i;
                int y = p / 5, x = p % 5;
                int iy = y + ky - 1, ix = x + kx - 1;
                if (iy < 0 || iy > 4 || ix < 0 || ix > 4) continue;
                cacc[i] += w * row[iy * 5 + ix];
            }
        }
    }
    #pragma unroll
    for (int i = 0; i < NP; i++) {
        float v = fmaxf(cacc[i], 0.f);
        unsigned short h, l;
        split_hl(v, h, l);
        a2h[kbase + P0 + i] = h;
        a2l[kbase + P0 + i] = l;
    }
}

// ===================== mega-kernel: phi pipeline ===========================
// Per (16-sample tile, phi). Phase-D split into two 64-z passes keeps peak
// register demand < 128/wave so __launch_bounds__(256,4) fits WITHOUT spills.
__global__ __launch_bounds__(256, 4) void k_phi(
    const int* __restrict__ s, const int* __restrict__ sp,
    const float* __restrict__ T, const float* __restrict__ beff,
    const float* __restrict__ w2a, const float* __restrict__ b2a,
    const float* __restrict__ w2b, const float* __restrict__ b2b,
    const unsigned short* __restrict__ wh, const unsigned short* __restrict__ wl,
    const float* __restrict__ lba, const float* __restrict__ lbb,
    const unsigned short* __restrict__ znh, const unsigned short* __restrict__ znl,
    float* __restrict__ Cm, int* __restrict__ idxout) {
    int phi = blockIdx.y;
    int b0 = blockIdx.x * 16;
    int tid = threadIdx.x;
    int wv = tid >> 6, lane = tid & 63, li = lane & 15, quad = lane >> 4;

    __shared__ __align__(16) char smem[37376];
    float* a1s          = (float*)smem;                    // [16][452] f32 (rows c1*28+p)
    unsigned short* a2h = (unsigned short*)(smem + 28928); // [16][120] u16
    unsigned short* a2l = (unsigned short*)(smem + 32768); // [16][120]
    int* sbase1         = (int*)(smem + 28928);            // overlay (phase A only)
    int* sbase2         = (int*)(smem + 30528);
    float* redq         = (float*)(smem + 36608);          // [16][4]
    float* argv         = (float*)(smem + 36864);          // [16][4]
    int*   argn         = (int*)(smem + 37120);            // [16][4]
    unsigned short* emh = (unsigned short*)smem;           // overlay a1s: [16][264]
    unsigned short* eml = (unsigned short*)(smem + 8448);

    const float* Tg = T + (size_t)phi * (25 * DICT * 400);

    // ---- load index bases (premultiplied T row offsets) ----
    for (int i = tid; i < 400; i += 256) {
        int si = i / 25, q = i - si * 25;
        sbase1[i] = (q * DICT + s[(b0 + si) * 25 + q]) * 400;
        if (phi) sbase2[i] = (q * DICT + sp[(b0 + si) * 25 + q]) * 400;
    }
    __syncthreads();

    // ---- phase A: conv1 table gather (float4) -> a1s (relu'd, padded) ----
    const float* be = beff + phi * 400;
    for (int task = tid; task < 1600; task += 256) {
        int si = task / 100, t4 = task - si * 100;
        int j = t4 * 4;
        float4 bv = *(const float4*)&be[j];
        float a0 = bv.x, a1v = bv.y, a2v = bv.z, a3v = bv.w;
        if (phi == 0) {
            const int* sb = sbase1 + si * 25;
            #pragma unroll
            for (int q = 0; q < 25; q++) {
                float4 t = *(const float4*)&Tg[sb[q] + j];
                a0 += t.x; a1v += t.y; a2v += t.z; a3v += t.w;
            }
        } else {
            const int* sb1 = sbase1 + si * 25;
            const int* sb2 = sbase2 + si * 25;
            #pragma unroll
            for (int q = 0; q < 25; q++) {
                float4 t2 = *(const float4*)&Tg[sb2[q] + j];
                float4 t1 = *(const float4*)&Tg[sb1[q] + j];
                a0 += t2.x - t1.x; a1v += t2.y - t1.y;
                a2v += t2.z - t1.z; a3v += t2.w - t1.w;
            }
        }
        float vals[4] = {a0, a1v, a2v, a3v};
        #pragma unroll
        for (int e = 0; e < 4; e++) {
            int jj = j + e;
            int c1 = jj / 25, p = jj - c1 * 25;
            a1s[si * 452 + c1 * 28 + p] = fmaxf(vals[e], 0.f);
        }
    }
    __syncthreads();   // sbase dead; a2 region reusable

    // ---- phases B+GEMM2: conv2 chunks (4 o2 = 100 k) -> linear accum ----
    const float* w2 = phi ? w2b : w2a;
    const float* b2 = phi ? b2b : b2a;
    const unsigned short* Wh = wh + (size_t)phi * EDIM * 800;
    const unsigned short* Wl = wl + (size_t)phi * EDIM * 800;
    int n0w = wv * 64;
    f32x4 acc2[4];
    f32x4 zz = {0.f, 0.f, 0.f, 0.f};
    #pragma unroll
    for (int j = 0; j < 4; j++) acc2[j] = zz;
    bf16x8 zfrag = {0, 0, 0, 0, 0, 0, 0, 0};

    int csi = lane >> 2, o2loc = lane & 3;   // conv2: lane->(si,o2), wave->pixel quarter
    const float* a1row = &a1s[csi * 452];
    for (int c = 0; c < 8; c++) {
        int o2 = c * 4 + o2loc;
        float bias2 = b2[o2];
        int kbase = csi * 120 + o2loc * 25;
        if (wv == 0)      conv2_body<0, 7>(a1row, w2, o2, bias2, a2h, a2l, kbase);
        else if (wv == 1) conv2_body<7, 13>(a1row, w2, o2, bias2, a2h, a2l, kbase);
        else if (wv == 2) conv2_body<13, 19>(a1row, w2, o2, bias2, a2h, a2l, kbase);
        else              conv2_body<19, 25>(a1row, w2, o2, bias2, a2h, a2l, kbase);
        __syncthreads();
        // GEMM2: K-chunk = 100 (3 full 32-steps + one 4-wide tail on quad0)
        #pragma unroll
        for (int ks = 0; ks < 4; ks++) {
            bf16x8 ah, al;
            if (ks < 3) {
                int ko = ks * 32 + quad * 8;
                ah = *(const bf16x8*)&a2h[li * 120 + ko];
                al = *(const bf16x8*)&a2l[li * 120 + ko];
            } else {
                ah = zfrag; al = zfrag;
                if (quad == 0) {
                    ushort4 v = *(const ushort4*)&a2h[li * 120 + 96];
                    ah[0] = (short)v.x; ah[1] = (short)v.y; ah[2] = (short)v.z; ah[3] = (short)v.w;
                    ushort4 u = *(const ushort4*)&a2l[li * 120 + 96];
                    al[0] = (short)u.x; al[1] = (short)u.y; al[2] = (short)u.z; al[3] = (short)u.w;
                }
            }
            #pragma unroll
            for (int nt = 0; nt < 4; nt++) {
                size_t nrow = (size_t)(n0w + nt * 16 + li) * 800;
                bf16x8 bh, bl;
                if (ks < 3) {
                    size_t wo = nrow + c * 100 + ks * 32 + quad * 8;
                    bh = *(const bf16x8*)(Wh + wo);
                    bl = *(const bf16x8*)(Wl + wo);
                } else {
                    bh = zfrag; bl = zfrag;
                    if (quad == 0) {
                        size_t wo = nrow + c * 100 + 96;
                        ushort4 v = *(const ushort4*)(Wh + wo);
                        bh[0] = (short)v.x; bh[1] = (short)v.y; bh[2] = (short)v.z; bh[3] = (short)v.w;
                        ushort4 u = *(const ushort4*)(Wl + wo);
                        bl[0] = (short)u.x; bl[1] = (short)u.y; bl[2] = (short)u.z; bl[3] = (short)u.w;
                    }
                }
                acc2[nt] = __builtin_amdgcn_mfma_f32_16x16x32_bf16(ah, bh, acc2[nt], 0, 0, 0);
                acc2[nt] = __builtin_amdgcn_mfma_f32_16x16x32_bf16(ah, bl, acc2[nt], 0, 0, 0);
                acc2[nt] = __builtin_amdgcn_mfma_f32_16x16x32_bf16(al, bh, acc2[nt], 0, 0, 0);
            }
        }
        __syncthreads();   // a2 consumed before next chunk overwrites
    }

    // ---- phase C: bias + row-normalize + split -> embed h/l in LDS ----
    const float* lb = phi ? lbb : lba;
    float sq[4] = {0.f, 0.f, 0.f, 0.f};
    #pragma unroll
    for (int nt = 0; nt < 4; nt++) {
        float bsv = lb[n0w + nt * 16 + li];
        #pragma unroll
        for (int r = 0; r < 4; r++) {
            float v = acc2[nt][r] + bsv;
            acc2[nt][r] = v;
            sq[r] += v * v;
        }
    }
    #pragma unroll
    for (int off = 1; off < 16; off <<= 1)
        #pragma unroll
        for (int r = 0; r < 4; r++)
            sq[r] += __shfl_xor(sq[r], off, 64);
    if (li == 0) {
        #pragma unroll
        for (int r = 0; r < 4; r++)
            redq[(quad * 4 + r) * 4 + wv] = sq[r];
    }
    __syncthreads();
    #pragma unroll
    for (int r = 0; r < 4; r++) {
        int rowm = quad * 4 + r;
        float tot = redq[rowm * 4 + 0] + redq[rowm * 4 + 1] +
                    redq[rowm * 4 + 2] + redq[rowm * 4 + 3];
        float inv = 1.f / (sqrtf(tot) + 1e-4f);
        #pragma unroll
        for (int nt = 0; nt < 4; nt++) {
            float v = acc2[nt][r] * inv;
            unsigned short h, l;
            split_hl(v, h, l);
            int col = n0w + nt * 16 + li;
            emh[rowm * 264 + col] = h;
            eml[rowm * 264 + col] = l;
        }
    }
    __syncthreads();

    // ---- phase D: two 64-z passes (acc3[4] each) + phase E fused ----
    int zn0 = wv * 128;
    float bestr[4] = {-3.0e38f, -3.0e38f, -3.0e38f, -3.0e38f};
    int   bnr[4]   = {0, 0, 0, 0};
    for (int half = 0; half < 2; half++) {
        f32x4 acc3[4];
        #pragma unroll
        for (int j = 0; j < 4; j++) acc3[j] = zz;
        int nbase = zn0 + half * 64;
        #pragma unroll
        for (int ks = 0; ks < 8; ks++) {
            int ko = ks * 32 + quad * 8;
            bf16x8 ah = *(const bf16x8*)&emh[li * 264 + ko];
            bf16x8 al = *(const bf16x8*)&eml[li * 264 + ko];
            #pragma unroll
            for (int nt = 0; nt < 4; nt++) {
                size_t zo = (size_t)(nbase + nt * 16 + li) * EDIM + ko;
                bf16x8 bh = *(const bf16x8*)(znh + zo);
                bf16x8 bl = *(const bf16x8*)(znl + zo);
                acc3[nt] = __builtin_amdgcn_mfma_f32_16x16x32_bf16(ah, bh, acc3[nt], 0, 0, 0);
                acc3[nt] = __builtin_amdgcn_mfma_f32_16x16x32_bf16(ah, bl, acc3[nt], 0, 0, 0);
                acc3[nt] = __builtin_amdgcn_mfma_f32_16x16x32_bf16(al, bh, acc3[nt], 0, 0, 0);
            }
        }
        if (phi == 0) {
            #pragma unroll
            for (int nt = 0; nt < 4; nt++)
                #pragma unroll
                for (int r = 0; r < 4; r++)
                    Cm[(size_t)(b0 + quad * 4 + r) * NZV + nbase + nt * 16 + li] = acc3[nt][r];
        } else {
            // ascending-n scan with strict > keeps the lowest index on ties
            #pragma unroll
            for (int nt = 0; nt < 4; nt++) {
                int n = nbase + nt * 16 + li;
                #pragma unroll
                for (int r = 0; r < 4; r++) {
                    float v = acc3[nt][r];
                    if (v > bestr[r]) { bestr[r] = v; bnr[r] = n; }
                }
            }
        }
    }

    if (phi == 1) {
        #pragma unroll
        for (int r = 0; r < 4; r++) {
            float bv = bestr[r]; int nv = bnr[r];
            #pragma unroll
            for (int off = 1; off < 16; off <<= 1) {
                float ov = __shfl_xor(bv, off, 64);
                int   on = __shfl_xor(nv, off, 64);
                if (ov > bv || (ov == bv && on < nv)) { bv = ov; nv = on; }
            }
            if (li == 0) {
                int rowm = quad * 4 + r;
                argv[rowm * 4 + wv] = bv;
                argn[rowm * 4 + wv] = nv;
            }
        }
        __syncthreads();
        if (tid < 16) {
            float bv = argv[tid * 4]; int nv = argn[tid * 4];
            #pragma unroll
            for (int w = 1; w < 4; w++) {
                float v = argv[tid * 4 + w]; int n = argn[tid * 4 + w];
                if (v > bv || (v == bv && n < nv)) { bv = v; nv = n; }
            }
            idxout[b0 + tid] = nv;
        }
    }
}

// ---- output: out[i][j] = exp(scale) * G0[i][idx[j]] -----------------------
__global__ __launch_bounds__(256) void k_out(const float* __restrict__ C,
                                             const int* __restrict__ idx,
                                             const float* __restrict__ scale,
                                             float* __restrict__ out) {
    __shared__ float g[8][NZV];
    __shared__ int   id[2048];
    int i0 = blockIdx.y * 8;
    int j0 = blockIdx.x * 2048;
    float esc = expf(scale[0]);
    for (int u = threadIdx.x; u < 2048; u += 256) id[u] = idx[j0 + u];
    for (int u = threadIdx.x; u < 8 * NZV; u += 256) {
        int r = u >> 9, c = u & 511;
        g[r][c] = C[(size_t)(i0 + r) * NZV + c];
    }
    __syncthreads();
    int jb = threadIdx.x * 8;
    int myid[8];
    #pragma unroll
    for (int u = 0; u < 8; u++) myid[u] = id[jb + u];
    #pragma unroll
    for (int r = 0; r < 8; r++) {
        float4 o0, o1;
        o0.x = esc * g[r][myid[0]]; o0.y = esc * g[r][myid[1]];
        o0.z = esc * g[r][myid[2]]; o0.w = esc * g[r][myid[3]];
        o1.x = esc * g[r][myid[4]]; o1.y = esc * g[r][myid[5]];
        o1.z = esc * g[r][myid[6]]; o1.w = esc * g[r][myid[7]];
        float4* dst = (float4*)(out + (size_t)(i0 + r) * NB + j0 + jb);
        dst[0] = o0; dst[1] = o1;
    }
}

extern "C" void kernel_launch(void* const* d_in, const int* in_sizes, int n_in,
                              void* d_out, int out_size, void* d_ws, size_t ws_size,
                              hipStream_t stream) {
    const int*   s     = (const int*)d_in[0];
    const int*   sp    = (const int*)d_in[1];
    const float* tab   = (const float*)d_in[2];
    const float* wE    = (const float*)d_in[3];
    const float* bE    = (const float*)d_in[4];
    const float* w1a   = (const float*)d_in[5];
    const float* b1a   = (const float*)d_in[6];
    const float* w2a   = (const float*)d_in[7];
    const float* b2a   = (const float*)d_in[8];
    const float* lwa   = (const float*)d_in[9];
    const float* lba   = (const float*)d_in[10];
    const float* w1b   = (const float*)d_in[11];
    const float* b1b   = (const float*)d_in[12];
    const float* w2b   = (const float*)d_in[13];
    const float* b2b   = (const float*)d_in[14];
    const float* lwb   = (const float*)d_in[15];
    const float* lbb   = (const float*)d_in[16];
    const float* zv    = (const float*)d_in[17];
    const float* scale = (const float*)d_in[18];

    float* out = (float*)d_out;
    float* wsf = (float*)d_ws;

    // d_ws layout (float units), ~20.1 MB total
    float* tn   = wsf;                                        // [0, 448)
    float* Aw   = wsf + 448;                                  // [448, 8512)
    float* beff = wsf + 8512;                                 // [8512, 9312)
    int*   idx  = (int*)(wsf + 9312);                         // [9312, 17504)
    float* T    = wsf + 17504;                                // [17504, 297504)
    float* Cm   = wsf + 297504;                               // 8192*512 -> [.., 4491808)
    unsigned short* wh  = (unsigned short*)(wsf + 4491808);   // 409600 u16
    unsigned short* wl  = (unsigned short*)(wsf + 4696608);
    unsigned short* znh = (unsigned short*)(wsf + 4901408);   // 131072 u16
    unsigned short* znl = (unsigned short*)(wsf + 4966944);   // ends 5032480

    k_norm_embed<<<DICT, 64, 0, stream>>>(tab, tn);
    k_prep_zw<<<NZV + 1600, 256, 0, stream>>>(zv, lwa, lwb, znh, znl, wh, wl);
    k_prep_ab<<<34, 256, 0, stream>>>(wE, tn, w1a, b1a, w1b, b1b, bE, Aw, beff);
    k_build_T<<<dim3(25 * DICT, 2), 256, 0, stream>>>(w1a, w1b, Aw, T);
    k_phi<<<dim3(NB / 16, 2), 256, 0, stream>>>(s, sp, T, beff, w2a, b2a, w2b, b2b,
                                                wh, wl, lba, lbb, znh, znl, Cm, idx);
    k_out<<<dim3(NB / 2048, NB / 8), 256, 0, stream>>>(Cm, idx, scale, out);
}

// Round 6
// 636.778 us; speedup vs baseline: 1.0616x; 1.0616x over previous
//
#include <hip/hip_runtime.h>
#include <hip/hip_bf16.h>

#define NB    8192
#define DICT  14
#define SE    32
#define CC    64
#define EDIM  256
#define NZV   512
#define C1N   16
#define C2N   32

typedef __attribute__((ext_vector_type(8))) short bf16x8;
typedef __attribute__((ext_vector_type(4))) float f32x4;

// split fp32 -> bf16 hi (truncate) + bf16 lo (RNE of residual); 3-term MFMA
__device__ __forceinline__ void split_hl(float x, unsigned short& h, unsigned short& l) {
    unsigned u = __float_as_uint(x);
    unsigned short hh = (unsigned short)(u >> 16);
    float hf = __uint_as_float((unsigned)hh << 16);
    float lof = x - hf;
    unsigned ul = __float_as_uint(lof);
    l = (unsigned short)((ul + 0x7FFFu + ((ul >> 16) & 1u)) >> 16);
    h = hh;
}

// ---------------- prep: normalize embedding rows (max_norm=1) --------------
__global__ __launch_bounds__(64) void k_norm_embed(const float* __restrict__ tab,
                                                   float* __restrict__ tn) {
    int d = blockIdx.x, l = threadIdx.x;
    float v = (l < SE) ? tab[d * SE + l] : 0.f;
    float s = v * v;
    #pragma unroll
    for (int o = 32; o > 0; o >>= 1) s += __shfl_down(s, o, 64);
    s = __shfl(s, 0, 64);
    float sc = fminf(1.f, 1.f / (sqrtf(s) + 1e-7f));
    if (l < SE) tn[d * SE + l] = v * sc;
}

// ---- norm z (h/l bf16) + split linear weights, one launch -----------------
__global__ __launch_bounds__(256) void k_prep_zw(const float* __restrict__ z,
        const float* __restrict__ lwa, const float* __restrict__ lwb,
        unsigned short* __restrict__ znh, unsigned short* __restrict__ znl,
        unsigned short* __restrict__ wh, unsigned short* __restrict__ wl) {
    int bid = blockIdx.x, t = threadIdx.x;
    if (bid < NZV) {
        __shared__ float red[4];
        float v = z[bid * EDIM + t];
        float s = v * v;
        #pragma unroll
        for (int o = 32; o > 0; o >>= 1) s += __shfl_down(s, o, 64);
        if ((t & 63) == 0) red[t >> 6] = s;
        __syncthreads();
        float tot = red[0] + red[1] + red[2] + red[3];
        float nv = v / sqrtf(tot);
        unsigned short h, l;
        split_hl(nv, h, l);
        znh[bid * EDIM + t] = h;
        znl[bid * EDIM + t] = l;
    } else {
        int i = (bid - NZV) * 256 + t;            // [2][256][800]
        if (i < 2 * EDIM * 800) {
            float v = (i < EDIM * 800) ? lwa[i] : lwb[i - EDIM * 800];
            unsigned short h, l;
            split_hl(v, h, l);
            wh[i] = h; wl[i] = l;
        }
    }
}

// ---- build_A + build_beff merged ------------------------------------------
__global__ __launch_bounds__(256) void k_prep_ab(const float* __restrict__ we,
        const float* __restrict__ tn,
        const float* __restrict__ w1a, const float* __restrict__ b1a,
        const float* __restrict__ w1b, const float* __restrict__ b1b,
        const float* __restrict__ be,
        float* __restrict__ A, float* __restrict__ beff) {
    if (blockIdx.x < 32) {
        int i = blockIdx.x * 256 + threadIdx.x;
        if (i >= DICT * CC * 9) return;
        int f = i % 9, c1 = (i / 9) % CC, d = i / (9 * CC);
        float acc = 0.f;
        #pragma unroll
        for (int c0 = 0; c0 < SE; c0++) acc += we[(c1 * SE + c0) * 9 + f] * tn[d * SE + c0];
        A[i] = acc;
    } else {
        int t = blockIdx.x - 32;
        const float* w1 = t ? w1b : w1a;
        const float* b1 = t ? b1b : b1a;
        for (int j = threadIdx.x; j < 400; j += blockDim.x) {
            int o = j / 25, y = (j / 5) % 5, x = j % 5;
            float acc = b1[o];
            if (t == 0) {
                for (int ey = 0; ey < 3; ey++) {
                    int py = y + ey - 1; if (py < 0 || py > 4) continue;
                    for (int ex = 0; ex < 3; ex++) {
                        int px = x + ex - 1; if (px < 0 || px > 4) continue;
                        for (int c1 = 0; c1 < CC; c1++)
                            acc += w1[((o * CC + c1) * 3 + ey) * 3 + ex] * be[c1];
                    }
                }
            }
            beff[t * 400 + j] = acc;
        }
    }
}

// ---- T[t][q][d][j] = composed conv1(conv_embed(onehot)) table -------------
__global__ __launch_bounds__(256) void k_build_T(const float* __restrict__ w1a,
                                                 const float* __restrict__ w1b,
                                                 const float* __restrict__ A,
                                                 float* __restrict__ T) {
    int t = blockIdx.y;
    int qd = blockIdx.x;
    int d = qd % DICT, q = qd / DICT;
    int qy = q / 5, qx = q % 5;
    const float* w1 = t ? w1b : w1a;
    __shared__ float w1s[C1N * CC * 9];
    __shared__ float As[CC * 9];
    for (int i = threadIdx.x; i < C1N * CC * 9; i += 256) w1s[i] = w1[i];
    for (int i = threadIdx.x; i < CC * 9; i += 256) As[i] = A[d * CC * 9 + i];
    __syncthreads();
    float* Tout = T + (((size_t)t * 25 + q) * DICT + d) * 400;
    for (int j = threadIdx.x; j < 400; j += 256) {
        int o = j / 25, y = (j / 5) % 5, x = j % 5;
        float acc = 0.f;
        int py0 = max(0, max(y - 1, qy - 1)), py1 = min(4, min(y + 1, qy + 1));
        int px0 = max(0, max(x - 1, qx - 1)), px1 = min(4, min(x + 1, qx + 1));
        for (int py = py0; py <= py1; py++)
            for (int px = px0; px <= px1; px++) {
                int ey = py - y + 1, ex = px - x + 1;
                int fy = qy - py + 1, fx = qx - px + 1;
                const float* wp = &w1s[(o * CC) * 9 + (ey * 3 + ex)];
                const float* ap = &As[fy * 3 + fx];
                float pa = 0.f;
                #pragma unroll 8
                for (int c1 = 0; c1 < CC; c1++) pa += wp[c1 * 9] * ap[c1 * 9];
                acc += pa;
            }
        Tout[j] = acc;
    }
}

// conv2 pixel-quarter body: compile-time pixel range [P0,P1)
template<int P0, int P1>
__device__ __forceinline__ void conv2_body(const float* __restrict__ a1row,
                                           const float* __restrict__ w2,
                                           int o2, float bias2,
                                           unsigned short* __restrict__ a2h,
                                           unsigned short* __restrict__ a2l,
                                           int kbase) {
    constexpr int NP = P1 - P0;
    float cacc[NP];
    #pragma unroll
    for (int i = 0; i < NP; i++) cacc[i] = bias2;
    for (int c1 = 0; c1 < C1N; c1++) {
        const float* rp = a1row + c1 * 28;
        float row[25];
        #pragma unroll
        for (int v = 0; v < 6; v++) *(float4*)&row[v * 4] = *(const float4*)&rp[v * 4];
        row[24] = rp[24];
        const float* wp = &w2[(o2 * C1N + c1) * 9];
        #pragma unroll
        for (int ky = 0; ky < 3; ky++)
        #pragma unroll
        for (int kx = 0; kx < 3; kx++) {
            float w = wp[ky * 3 + kx];
            #pragma unroll
            for (int i = 0; i < NP; i++) {
                int p = P0 + i;
                int y = p / 5, x = p % 5;
                int iy = y + ky - 1, ix = x + kx - 1;
                if (iy < 0 || iy > 4 || ix < 0 || ix > 4) continue;
                cacc[i] += w * row[iy * 5 + ix];
            }
        }
    }
    #pragma unroll
    for (int i = 0; i < NP; i++) {
        float v = fmaxf(cacc[i], 0.f);
        unsigned short h, l;
        split_hl(v, h, l);
        a2h[kbase + P0 + i] = h;
        a2l[kbase + P0 + i] = l;
    }
}

// ===================== mega-kernel: phi pipeline ===========================
// Per (16-sample tile, phi). __launch_bounds__(256,3): 170 regs/wave ->
// conv2 fits WITHOUT scratch spills; LDS 36.5K x3 = 109.5K -> 3 blocks/CU.
__global__ __launch_bounds__(256, 3) void k_phi(
    const int* __restrict__ s, const int* __restrict__ sp,
    const float* __restrict__ T, const float* __restrict__ beff,
    const float* __restrict__ w2a, const float* __restrict__ b2a,
    const float* __restrict__ w2b, const float* __restrict__ b2b,
    const unsigned short* __restrict__ wh, const unsigned short* __restrict__ wl,
    const float* __restrict__ lba, const float* __restrict__ lbb,
    const unsigned short* __restrict__ znh, const unsigned short* __restrict__ znl,
    float* __restrict__ Cm, int* __restrict__ idxout) {
    int phi = blockIdx.y;
    int b0 = blockIdx.x * 16;
    int tid = threadIdx.x;
    int wv = tid >> 6, lane = tid & 63, li = lane & 15, quad = lane >> 4;

    __shared__ __align__(16) char smem[37376];
    float* a1s          = (float*)smem;                    // [16][452] f32 (rows c1*28+p)
    unsigned short* a2h = (unsigned short*)(smem + 28928); // [16][120] u16
    unsigned short* a2l = (unsigned short*)(smem + 32768); // [16][120]
    int* sbase1         = (int*)(smem + 28928);            // overlay (phase A only)
    int* sbase2         = (int*)(smem + 30528);
    float* redq         = (float*)(smem + 36608);          // [16][4]
    float* argv         = (float*)(smem + 36864);          // [16][4]
    int*   argn         = (int*)(smem + 37120);            // [16][4]
    unsigned short* emh = (unsigned short*)smem;           // overlay a1s: [16][264]
    unsigned short* eml = (unsigned short*)(smem + 8448);

    const float* Tg = T + (size_t)phi * (25 * DICT * 400);

    // ---- load index bases (premultiplied T row offsets) ----
    for (int i = tid; i < 400; i += 256) {
        int si = i / 25, q = i - si * 25;
        sbase1[i] = (q * DICT + s[(b0 + si) * 25 + q]) * 400;
        if (phi) sbase2[i] = (q * DICT + sp[(b0 + si) * 25 + q]) * 400;
    }
    __syncthreads();

    // ---- phase A: conv1 table gather (float4) -> a1s (relu'd, padded) ----
    const float* be = beff + phi * 400;
    for (int task = tid; task < 1600; task += 256) {
        int si = task / 100, t4 = task - si * 100;
        int j = t4 * 4;
        float4 bv = *(const float4*)&be[j];
        float a0 = bv.x, a1v = bv.y, a2v = bv.z, a3v = bv.w;
        if (phi == 0) {
            const int* sb = sbase1 + si * 25;
            #pragma unroll
            for (int q = 0; q < 25; q++) {
                float4 t = *(const float4*)&Tg[sb[q] + j];
                a0 += t.x; a1v += t.y; a2v += t.z; a3v += t.w;
            }
        } else {
            const int* sb1 = sbase1 + si * 25;
            const int* sb2 = sbase2 + si * 25;
            #pragma unroll
            for (int q = 0; q < 25; q++) {
                float4 t2 = *(const float4*)&Tg[sb2[q] + j];
                float4 t1 = *(const float4*)&Tg[sb1[q] + j];
                a0 += t2.x - t1.x; a1v += t2.y - t1.y;
                a2v += t2.z - t1.z; a3v += t2.w - t1.w;
            }
        }
        float vals[4] = {a0, a1v, a2v, a3v};
        #pragma unroll
        for (int e = 0; e < 4; e++) {
            int jj = j + e;
            int c1 = jj / 25, p = jj - c1 * 25;
            a1s[si * 452 + c1 * 28 + p] = fmaxf(vals[e], 0.f);
        }
    }
    __syncthreads();   // sbase dead; a2 region reusable

    // ---- phases B+GEMM2: conv2 chunks (4 o2 = 100 k) -> linear accum ----
    const float* w2 = phi ? w2b : w2a;
    const float* b2 = phi ? b2b : b2a;
    const unsigned short* Wh = wh + (size_t)phi * EDIM * 800;
    const unsigned short* Wl = wl + (size_t)phi * EDIM * 800;
    int n0w = wv * 64;
    f32x4 acc2[4];
    f32x4 zz = {0.f, 0.f, 0.f, 0.f};
    #pragma unroll
    for (int j = 0; j < 4; j++) acc2[j] = zz;
    bf16x8 zfrag = {0, 0, 0, 0, 0, 0, 0, 0};

    int csi = lane >> 2, o2loc = lane & 3;   // conv2: lane->(si,o2), wave->pixel quarter
    const float* a1row = &a1s[csi * 452];
    for (int c = 0; c < 8; c++) {
        int o2 = c * 4 + o2loc;
        float bias2 = b2[o2];
        int kbase = csi * 120 + o2loc * 25;
        if (wv == 0)      conv2_body<0, 7>(a1row, w2, o2, bias2, a2h, a2l, kbase);
        else if (wv == 1) conv2_body<7, 13>(a1row, w2, o2, bias2, a2h, a2l, kbase);
        else if (wv == 2) conv2_body<13, 19>(a1row, w2, o2, bias2, a2h, a2l, kbase);
        else              conv2_body<19, 25>(a1row, w2, o2, bias2, a2h, a2l, kbase);
        __syncthreads();
        // GEMM2: K-chunk = 100 (3 full 32-steps + one 4-wide tail on quad0)
        #pragma unroll
        for (int ks = 0; ks < 4; ks++) {
            bf16x8 ah, al;
            if (ks < 3) {
                int ko = ks * 32 + quad * 8;
                ah = *(const bf16x8*)&a2h[li * 120 + ko];
                al = *(const bf16x8*)&a2l[li * 120 + ko];
            } else {
                ah = zfrag; al = zfrag;
                if (quad == 0) {
                    ushort4 v = *(const ushort4*)&a2h[li * 120 + 96];
                    ah[0] = (short)v.x; ah[1] = (short)v.y; ah[2] = (short)v.z; ah[3] = (short)v.w;
                    ushort4 u = *(const ushort4*)&a2l[li * 120 + 96];
                    al[0] = (short)u.x; al[1] = (short)u.y; al[2] = (short)u.z; al[3] = (short)u.w;
                }
            }
            #pragma unroll
            for (int nt = 0; nt < 4; nt++) {
                size_t nrow = (size_t)(n0w + nt * 16 + li) * 800;
                bf16x8 bh, bl;
                if (ks < 3) {
                    size_t wo = nrow + c * 100 + ks * 32 + quad * 8;
                    bh = *(const bf16x8*)(Wh + wo);
                    bl = *(const bf16x8*)(Wl + wo);
                } else {
                    bh = zfrag; bl = zfrag;
                    if (quad == 0) {
                        size_t wo = nrow + c * 100 + 96;
                        ushort4 v = *(const ushort4*)(Wh + wo);
                        bh[0] = (short)v.x; bh[1] = (short)v.y; bh[2] = (short)v.z; bh[3] = (short)v.w;
                        ushort4 u = *(const ushort4*)(Wl + wo);
                        bl[0] = (short)u.x; bl[1] = (short)u.y; bl[2] = (short)u.z; bl[3] = (short)u.w;
                    }
                }
                acc2[nt] = __builtin_amdgcn_mfma_f32_16x16x32_bf16(ah, bh, acc2[nt], 0, 0, 0);
                acc2[nt] = __builtin_amdgcn_mfma_f32_16x16x32_bf16(ah, bl, acc2[nt], 0, 0, 0);
                acc2[nt] = __builtin_amdgcn_mfma_f32_16x16x32_bf16(al, bh, acc2[nt], 0, 0, 0);
            }
        }
        __syncthreads();   // a2 consumed before next chunk overwrites
    }

    // ---- phase C: bias + row-normalize + split -> embed h/l in LDS ----
    const float* lb = phi ? lbb : lba;
    float sq[4] = {0.f, 0.f, 0.f, 0.f};
    #pragma unroll
    for (int nt = 0; nt < 4; nt++) {
        float bsv = lb[n0w + nt * 16 + li];
        #pragma unroll
        for (int r = 0; r < 4; r++) {
            float v = acc2[nt][r] + bsv;
            acc2[nt][r] = v;
            sq[r] += v * v;
        }
    }
    #pragma unroll
    for (int off = 1; off < 16; off <<= 1)
        #pragma unroll
        for (int r = 0; r < 4; r++)
            sq[r] += __shfl_xor(sq[r], off, 64);
    if (li == 0) {
        #pragma unroll
        for (int r = 0; r < 4; r++)
            redq[(quad * 4 + r) * 4 + wv] = sq[r];
    }
    __syncthreads();
    #pragma unroll
    for (int r = 0; r < 4; r++) {
        int rowm = quad * 4 + r;
        float tot = redq[rowm * 4 + 0] + redq[rowm * 4 + 1] +
                    redq[rowm * 4 + 2] + redq[rowm * 4 + 3];
        float inv = 1.f / (sqrtf(tot) + 1e-4f);
        #pragma unroll
        for (int nt = 0; nt < 4; nt++) {
            float v = acc2[nt][r] * inv;
            unsigned short h, l;
            split_hl(v, h, l);
            int col = n0w + nt * 16 + li;
            emh[rowm * 264 + col] = h;
            eml[rowm * 264 + col] = l;
        }
    }
    __syncthreads();

    // ---- phase D: two 64-z passes (acc3[4] each) + phase E fused ----
    int zn0 = wv * 128;
    float bestr[4] = {-3.0e38f, -3.0e38f, -3.0e38f, -3.0e38f};
    int   bnr[4]   = {0, 0, 0, 0};
    for (int half = 0; half < 2; half++) {
        f32x4 acc3[4];
        #pragma unroll
        for (int j = 0; j < 4; j++) acc3[j] = zz;
        int nbase = zn0 + half * 64;
        #pragma unroll
        for (int ks = 0; ks < 8; ks++) {
            int ko = ks * 32 + quad * 8;
            bf16x8 ah = *(const bf16x8*)&emh[li * 264 + ko];
            bf16x8 al = *(const bf16x8*)&eml[li * 264 + ko];
            #pragma unroll
            for (int nt = 0; nt < 4; nt++) {
                size_t zo = (size_t)(nbase + nt * 16 + li) * EDIM + ko;
                bf16x8 bh = *(const bf16x8*)(znh + zo);
                bf16x8 bl = *(const bf16x8*)(znl + zo);
                acc3[nt] = __builtin_amdgcn_mfma_f32_16x16x32_bf16(ah, bh, acc3[nt], 0, 0, 0);
                acc3[nt] = __builtin_amdgcn_mfma_f32_16x16x32_bf16(ah, bl, acc3[nt], 0, 0, 0);
                acc3[nt] = __builtin_amdgcn_mfma_f32_16x16x32_bf16(al, bh, acc3[nt], 0, 0, 0);
            }
        }
        if (phi == 0) {
            #pragma unroll
            for (int nt = 0; nt < 4; nt++)
                #pragma unroll
                for (int r = 0; r < 4; r++)
                    Cm[(size_t)(b0 + quad * 4 + r) * NZV + nbase + nt * 16 + li] = acc3[nt][r];
        } else {
            // ascending-n scan with strict > keeps the lowest index on ties
            #pragma unroll
            for (int nt = 0; nt < 4; nt++) {
                int n = nbase + nt * 16 + li;
                #pragma unroll
                for (int r = 0; r < 4; r++) {
                    float v = acc3[nt][r];
                    if (v > bestr[r]) { bestr[r] = v; bnr[r] = n; }
                }
            }
        }
    }

    if (phi == 1) {
        #pragma unroll
        for (int r = 0; r < 4; r++) {
            float bv = bestr[r]; int nv = bnr[r];
            #pragma unroll
            for (int off = 1; off < 16; off <<= 1) {
                float ov = __shfl_xor(bv, off, 64);
                int   on = __shfl_xor(nv, off, 64);
                if (ov > bv || (ov == bv && on < nv)) { bv = ov; nv = on; }
            }
            if (li == 0) {
                int rowm = quad * 4 + r;
                argv[rowm * 4 + wv] = bv;
                argn[rowm * 4 + wv] = nv;
            }
        }
        __syncthreads();
        if (tid < 16) {
            float bv = argv[tid * 4]; int nv = argn[tid * 4];
            #pragma unroll
            for (int w = 1; w < 4; w++) {
                float v = argv[tid * 4 + w]; int n = argn[tid * 4 + w];
                if (v > bv || (v == bv && n < nv)) { bv = v; nv = n; }
            }
            idxout[b0 + tid] = nv;
        }
    }
}

// ---- output: out[i][j] = exp(scale) * G0[i][idx[j]] -----------------------
__global__ __launch_bounds__(256) void k_out(const float* __restrict__ C,
                                             const int* __restrict__ idx,
                                             const float* __restrict__ scale,
                                             float* __restrict__ out) {
    __shared__ float g[8][NZV];
    __shared__ int   id[2048];
    int i0 = blockIdx.y * 8;
    int j0 = blockIdx.x * 2048;
    float esc = expf(scale[0]);
    for (int u = threadIdx.x; u < 2048; u += 256) id[u] = idx[j0 + u];
    for (int u = threadIdx.x; u < 8 * NZV; u += 256) {
        int r = u >> 9, c = u & 511;
        g[r][c] = C[(size_t)(i0 + r) * NZV + c];
    }
    __syncthreads();
    int jb = threadIdx.x * 8;
    int myid[8];
    #pragma unroll
    for (int u = 0; u < 8; u++) myid[u] = id[jb + u];
    #pragma unroll
    for (int r = 0; r < 8; r++) {
        float4 o0, o1;
        o0.x = esc * g[r][myid[0]]; o0.y = esc * g[r][myid[1]];
        o0.z = esc * g[r][myid[2]]; o0.w = esc * g[r][myid[3]];
        o1.x = esc * g[r][myid[4]]; o1.y = esc * g[r][myid[5]];
        o1.z = esc * g[r][myid[6]]; o1.w = esc * g[r][myid[7]];
        float4* dst = (float4*)(out + (size_t)(i0 + r) * NB + j0 + jb);
        dst[0] = o0; dst[1] = o1;
    }
}

extern "C" void kernel_launch(void* const* d_in, const int* in_sizes, int n_in,
                              void* d_out, int out_size, void* d_ws, size_t ws_size,
                              hipStream_t stream) {
    const int*   s     = (const int*)d_in[0];
    const int*   sp    = (const int*)d_in[1];
    const float* tab   = (const float*)d_in[2];
    const float* wE    = (const float*)d_in[3];
    const float* bE    = (const float*)d_in[4];
    const float* w1a   = (const float*)d_in[5];
    const float* b1a   = (const float*)d_in[6];
    const float* w2a   = (const float*)d_in[7];
    const float* b2a   = (const float*)d_in[8];
    const float* lwa   = (const float*)d_in[9];
    const float* lba   = (const float*)d_in[10];
    const float* w1b   = (const float*)d_in[11];
    const float* b1b   = (const float*)d_in[12];
    const float* w2b   = (const float*)d_in[13];
    const float* b2b   = (const float*)d_in[14];
    const float* lwb   = (const float*)d_in[15];
    const float* lbb   = (const float*)d_in[16];
    const float* zv    = (const float*)d_in[17];
    const float* scale = (const float*)d_in[18];

    float* out = (float*)d_out;
    float* wsf = (float*)d_ws;

    // d_ws layout (float units), ~20.1 MB total
    float* tn   = wsf;                                        // [0, 448)
    float* Aw   = wsf + 448;                                  // [448, 8512)
    float* beff = wsf + 8512;                                 // [8512, 9312)
    int*   idx  = (int*)(wsf + 9312);                         // [9312, 17504)
    float* T    = wsf + 17504;                                // [17504, 297504)
    float* Cm   = wsf + 297504;                               // 8192*512 -> [.., 4491808)
    unsigned short* wh  = (unsigned short*)(wsf + 4491808);   // 409600 u16
    unsigned short* wl  = (unsigned short*)(wsf + 4696608);
    unsigned short* znh = (unsigned short*)(wsf + 4901408);   // 131072 u16
    unsigned short* znl = (unsigned short*)(wsf + 4966944);   // ends 5032480

    k_norm_embed<<<DICT, 64, 0, stream>>>(tab, tn);
    k_prep_zw<<<NZV + 1600, 256, 0, stream>>>(zv, lwa, lwb, znh, znl, wh, wl);
    k_prep_ab<<<34, 256, 0, stream>>>(wE, tn, w1a, b1a, w1b, b1b, bE, Aw, beff);
    k_build_T<<<dim3(25 * DICT, 2), 256, 0, stream>>>(w1a, w1b, Aw, T);
    k_phi<<<dim3(NB / 16, 2), 256, 0, stream>>>(s, sp, T, beff, w2a, b2a, w2b, b2b,
                                                wh, wl, lba, lbb, znh, znl, Cm, idx);
    k_out<<<dim3(NB / 2048, NB / 8), 256, 0, stream>>>(Cm, idx, scale, out);
}

// Round 7
// 557.993 us; speedup vs baseline: 1.2115x; 1.1412x over previous
//
#include <hip/hip_runtime.h>
#include <hip/hip_bf16.h>

#define NB    8192
#define DICT  14
#define SE    32
#define CC    64
#define EDIM  256
#define NZV   512
#define C1N   16
#define C2N   32

typedef __attribute__((ext_vector_type(8))) short bf16x8;
typedef __attribute__((ext_vector_type(4))) float f32x4;

// split fp32 -> bf16 hi (truncate) + bf16 lo (RNE of residual); 3-term MFMA
__device__ __forceinline__ void split_hl(float x, unsigned short& h, unsigned short& l) {
    unsigned u = __float_as_uint(x);
    unsigned short hh = (unsigned short)(u >> 16);
    float hf = __uint_as_float((unsigned)hh << 16);
    float lof = x - hf;
    unsigned ul = __float_as_uint(lof);
    l = (unsigned short)((ul + 0x7FFFu + ((ul >> 16) & 1u)) >> 16);
    h = hh;
}

// ---------------- prep: normalize embedding rows (max_norm=1) --------------
__global__ __launch_bounds__(64) void k_norm_embed(const float* __restrict__ tab,
                                                   float* __restrict__ tn) {
    int d = blockIdx.x, l = threadIdx.x;
    float v = (l < SE) ? tab[d * SE + l] : 0.f;
    float s = v * v;
    #pragma unroll
    for (int o = 32; o > 0; o >>= 1) s += __shfl_down(s, o, 64);
    s = __shfl(s, 0, 64);
    float sc = fminf(1.f, 1.f / (sqrtf(s) + 1e-7f));
    if (l < SE) tn[d * SE + l] = v * sc;
}

// ---- norm z (h/l bf16) + split linear weights, one launch -----------------
__global__ __launch_bounds__(256) void k_prep_zw(const float* __restrict__ z,
        const float* __restrict__ lwa, const float* __restrict__ lwb,
        unsigned short* __restrict__ znh, unsigned short* __restrict__ znl,
        unsigned short* __restrict__ wh, unsigned short* __restrict__ wl) {
    int bid = blockIdx.x, t = threadIdx.x;
    if (bid < NZV) {
        __shared__ float red[4];
        float v = z[bid * EDIM + t];
        float s = v * v;
        #pragma unroll
        for (int o = 32; o > 0; o >>= 1) s += __shfl_down(s, o, 64);
        if ((t & 63) == 0) red[t >> 6] = s;
        __syncthreads();
        float tot = red[0] + red[1] + red[2] + red[3];
        float nv = v / sqrtf(tot);
        unsigned short h, l;
        split_hl(nv, h, l);
        znh[bid * EDIM + t] = h;
        znl[bid * EDIM + t] = l;
    } else {
        int i = (bid - NZV) * 256 + t;            // [2][256][800]
        if (i < 2 * EDIM * 800) {
            float v = (i < EDIM * 800) ? lwa[i] : lwb[i - EDIM * 800];
            unsigned short h, l;
            split_hl(v, h, l);
            wh[i] = h; wl[i] = l;
        }
    }
}

// ---- build_A + build_beff merged ------------------------------------------
__global__ __launch_bounds__(256) void k_prep_ab(const float* __restrict__ we,
        const float* __restrict__ tn,
        const float* __restrict__ w1a, const float* __restrict__ b1a,
        const float* __restrict__ w1b, const float* __restrict__ b1b,
        const float* __restrict__ be,
        float* __restrict__ A, float* __restrict__ beff) {
    if (blockIdx.x < 32) {
        int i = blockIdx.x * 256 + threadIdx.x;
        if (i >= DICT * CC * 9) return;
        int f = i % 9, c1 = (i / 9) % CC, d = i / (9 * CC);
        float acc = 0.f;
        #pragma unroll
        for (int c0 = 0; c0 < SE; c0++) acc += we[(c1 * SE + c0) * 9 + f] * tn[d * SE + c0];
        A[i] = acc;
    } else {
        int t = blockIdx.x - 32;
        const float* w1 = t ? w1b : w1a;
        const float* b1 = t ? b1b : b1a;
        for (int j = threadIdx.x; j < 400; j += blockDim.x) {
            int o = j / 25, y = (j / 5) % 5, x = j % 5;
            float acc = b1[o];
            if (t == 0) {
                for (int ey = 0; ey < 3; ey++) {
                    int py = y + ey - 1; if (py < 0 || py > 4) continue;
                    for (int ex = 0; ex < 3; ex++) {
                        int px = x + ex - 1; if (px < 0 || px > 4) continue;
                        for (int c1 = 0; c1 < CC; c1++)
                            acc += w1[((o * CC + c1) * 3 + ey) * 3 + ex] * be[c1];
                    }
                }
            }
            beff[t * 400 + j] = acc;
        }
    }
}

// ---- T[t][q][d][j] = composed conv1(conv_embed(onehot)) table -------------
__global__ __launch_bounds__(256) void k_build_T(const float* __restrict__ w1a,
                                                 const float* __restrict__ w1b,
                                                 const float* __restrict__ A,
                                                 float* __restrict__ T) {
    int t = blockIdx.y;
    int qd = blockIdx.x;
    int d = qd % DICT, q = qd / DICT;
    int qy = q / 5, qx = q % 5;
    const float* w1 = t ? w1b : w1a;
    __shared__ float w1s[C1N * CC * 9];
    __shared__ float As[CC * 9];
    for (int i = threadIdx.x; i < C1N * CC * 9; i += 256) w1s[i] = w1[i];
    for (int i = threadIdx.x; i < CC * 9; i += 256) As[i] = A[d * CC * 9 + i];
    __syncthreads();
    float* Tout = T + (((size_t)t * 25 + q) * DICT + d) * 400;
    for (int j = threadIdx.x; j < 400; j += 256) {
        int o = j / 25, y = (j / 5) % 5, x = j % 5;
        float acc = 0.f;
        int py0 = max(0, max(y - 1, qy - 1)), py1 = min(4, min(y + 1, qy + 1));
        int px0 = max(0, max(x - 1, qx - 1)), px1 = min(4, min(x + 1, qx + 1));
        for (int py = py0; py <= py1; py++)
            for (int px = px0; px <= px1; px++) {
                int ey = py - y + 1, ex = px - x + 1;
                int fy = qy - py + 1, fx = qx - px + 1;
                const float* wp = &w1s[(o * CC) * 9 + (ey * 3 + ex)];
                const float* ap = &As[fy * 3 + fx];
                float pa = 0.f;
                #pragma unroll 8
                for (int c1 = 0; c1 < CC; c1++) pa += wp[c1 * 9] * ap[c1 * 9];
                acc += pa;
            }
        Tout[j] = acc;
    }
}

// =================== k_gcv: conv1-gather + conv2 -> a2 (global) ============
// NO MFMA in this kernel => no AGPR pressure => (256,4) fits 128 VGPRs.
// 16-sample tile, LDS ~32 KB, 2 barriers. a2 layout [phi][b][k=o2*25+p] h/l.
__global__ __launch_bounds__(256, 4) void k_gcv(
    const int* __restrict__ s, const int* __restrict__ sp,
    const float* __restrict__ T, const float* __restrict__ beff,
    const float* __restrict__ w2a, const float* __restrict__ b2a,
    const float* __restrict__ w2b, const float* __restrict__ b2b,
    unsigned short* __restrict__ a2h, unsigned short* __restrict__ a2l) {
    int phi = blockIdx.y;
    int b0 = blockIdx.x * 16;
    int tid = threadIdx.x;

    __shared__ int sbase1[400], sbase2[400];
    __shared__ __align__(16) float a1s[16 * 452];   // [si][c1*28+p], 28.9 KB

    const float* Tg = T + (size_t)phi * (25 * DICT * 400);

    for (int i = tid; i < 400; i += 256) {
        int si = i / 25, q = i - si * 25;
        sbase1[i] = (q * DICT + s[(b0 + si) * 25 + q]) * 400;
        if (phi) sbase2[i] = (q * DICT + sp[(b0 + si) * 25 + q]) * 400;
    }
    __syncthreads();

    // phase A: conv1 table gather (float4) -> a1s (relu'd, padded)
    const float* be = beff + phi * 400;
    for (int task = tid; task < 1600; task += 256) {
        int si = task / 100, t4 = task - si * 100;
        int j = t4 * 4;
        float4 bv = *(const float4*)&be[j];
        float a0 = bv.x, a1v = bv.y, a2v = bv.z, a3v = bv.w;
        if (phi == 0) {
            const int* sb = sbase1 + si * 25;
            #pragma unroll
            for (int q = 0; q < 25; q++) {
                float4 t = *(const float4*)&Tg[sb[q] + j];
                a0 += t.x; a1v += t.y; a2v += t.z; a3v += t.w;
            }
        } else {
            const int* sb1 = sbase1 + si * 25;
            const int* sb2 = sbase2 + si * 25;
            #pragma unroll
            for (int q = 0; q < 25; q++) {
                float4 t2 = *(const float4*)&Tg[sb2[q] + j];
                float4 t1 = *(const float4*)&Tg[sb1[q] + j];
                a0 += t2.x - t1.x; a1v += t2.y - t1.y;
                a2v += t2.z - t1.z; a3v += t2.w - t1.w;
            }
        }
        float vals[4] = {a0, a1v, a2v, a3v};
        #pragma unroll
        for (int e = 0; e < 4; e++) {
            int jj = j + e;
            int c1 = jj / 25, p = jj - c1 * 25;
            a1s[si * 452 + c1 * 28 + p] = fmaxf(vals[e], 0.f);
        }
    }
    __syncthreads();

    // phase B: conv2, thread = (csi, oh); each thread 2 o2 x full 25 pixels
    const float* w2 = phi ? w2b : w2a;
    const float* b2 = phi ? b2b : b2a;
    int csi = tid >> 4, oh = tid & 15;
    const float* a1row = &a1s[csi * 452];
    size_t obase = ((size_t)phi * NB + b0 + csi) * 800;
    for (int t2 = 0; t2 < 2; t2++) {
        int o2 = oh * 2 + t2;
        float cacc[25];
        float bias2 = b2[o2];
        #pragma unroll
        for (int p = 0; p < 25; p++) cacc[p] = bias2;
        for (int c1 = 0; c1 < C1N; c1++) {
            const float* rp = a1row + c1 * 28;
            float row[25];
            #pragma unroll
            for (int v = 0; v < 6; v++) *(float4*)&row[v * 4] = *(const float4*)&rp[v * 4];
            row[24] = rp[24];
            const float* wp = &w2[(o2 * C1N + c1) * 9];
            #pragma unroll
            for (int ky = 0; ky < 3; ky++)
            #pragma unroll
            for (int kx = 0; kx < 3; kx++) {
                float w = wp[ky * 3 + kx];
                #pragma unroll
                for (int y = 0; y < 5; y++) {
                    int iy = y + ky - 1; if (iy < 0 || iy > 4) continue;
                    #pragma unroll
                    for (int x = 0; x < 5; x++) {
                        int ix = x + kx - 1; if (ix < 0 || ix > 4) continue;
                        cacc[y * 5 + x] += w * row[iy * 5 + ix];
                    }
                }
            }
        }
        size_t kb = obase + o2 * 25;
        #pragma unroll
        for (int p = 0; p < 25; p++) {
            float v = fmaxf(cacc[p], 0.f);
            unsigned short h, l;
            split_hl(v, h, l);
            a2h[kb + p] = h;
            a2l[kb + p] = l;
        }
    }
}

// ============ k_emb: GEMM2(K=800) + bias/norm + scores + argmax/Cm =========
// 32-sample tile, A-frags direct from global a2, straight 25 k-steps.
__global__ __launch_bounds__(256) void k_emb(
    const unsigned short* __restrict__ a2h, const unsigned short* __restrict__ a2l,
    const unsigned short* __restrict__ wh, const unsigned short* __restrict__ wl,
    const float* __restrict__ lba, const float* __restrict__ lbb,
    const unsigned short* __restrict__ znh, const unsigned short* __restrict__ znl,
    float* __restrict__ Cm, int* __restrict__ idxout) {
    int phi = blockIdx.y;
    int b0 = blockIdx.x * 32;
    int tid = threadIdx.x;
    int wv = tid >> 6, lane = tid & 63, li = lane & 15, quad = lane >> 4;

    __shared__ __align__(16) unsigned short emh[32 * 264], eml[32 * 264];  // 33.8 KB
    __shared__ float redq[32 * 4];
    __shared__ float argv[32 * 4];
    __shared__ int   argn[32 * 4];

    const unsigned short* Ah = a2h + ((size_t)phi * NB + b0) * 800;
    const unsigned short* Al = a2l + ((size_t)phi * NB + b0) * 800;
    const unsigned short* Wh = wh + (size_t)phi * EDIM * 800;
    const unsigned short* Wl = wl + (size_t)phi * EDIM * 800;
    int n0w = wv * 64;

    f32x4 zz = {0.f, 0.f, 0.f, 0.f};
    f32x4 acc2[2][4];
    #pragma unroll
    for (int i = 0; i < 2; i++)
        #pragma unroll
        for (int j = 0; j < 4; j++) acc2[i][j] = zz;

    for (int k0 = 0; k0 < 800; k0 += 32) {
        int ko = k0 + quad * 8;
        bf16x8 ah0 = *(const bf16x8*)(Ah + (size_t)li * 800 + ko);
        bf16x8 al0 = *(const bf16x8*)(Al + (size_t)li * 800 + ko);
        bf16x8 ah1 = *(const bf16x8*)(Ah + (size_t)(16 + li) * 800 + ko);
        bf16x8 al1 = *(const bf16x8*)(Al + (size_t)(16 + li) * 800 + ko);
        #pragma unroll
        for (int nt = 0; nt < 4; nt++) {
            size_t wo = (size_t)(n0w + nt * 16 + li) * 800 + ko;
            bf16x8 bh = *(const bf16x8*)(Wh + wo);
            bf16x8 bl = *(const bf16x8*)(Wl + wo);
            acc2[0][nt] = __builtin_amdgcn_mfma_f32_16x16x32_bf16(ah0, bh, acc2[0][nt], 0, 0, 0);
            acc2[0][nt] = __builtin_amdgcn_mfma_f32_16x16x32_bf16(ah0, bl, acc2[0][nt], 0, 0, 0);
            acc2[0][nt] = __builtin_amdgcn_mfma_f32_16x16x32_bf16(al0, bh, acc2[0][nt], 0, 0, 0);
            acc2[1][nt] = __builtin_amdgcn_mfma_f32_16x16x32_bf16(ah1, bh, acc2[1][nt], 0, 0, 0);
            acc2[1][nt] = __builtin_amdgcn_mfma_f32_16x16x32_bf16(ah1, bl, acc2[1][nt], 0, 0, 0);
            acc2[1][nt] = __builtin_amdgcn_mfma_f32_16x16x32_bf16(al1, bh, acc2[1][nt], 0, 0, 0);
        }
    }

    // phase C: bias + row-normalize + split -> embed h/l in LDS
    const float* lb = phi ? lbb : lba;
    float sq[2][4];
    #pragma unroll
    for (int mt = 0; mt < 2; mt++)
        #pragma unroll
        for (int r = 0; r < 4; r++) sq[mt][r] = 0.f;
    #pragma unroll
    for (int mt = 0; mt < 2; mt++)
        #pragma unroll
        for (int nt = 0; nt < 4; nt++) {
            float bsv = lb[n0w + nt * 16 + li];
            #pragma unroll
            for (int r = 0; r < 4; r++) {
                float v = acc2[mt][nt][r] + bsv;
                acc2[mt][nt][r] = v;
                sq[mt][r] += v * v;
            }
        }
    #pragma unroll
    for (int off = 1; off < 16; off <<= 1)
        #pragma unroll
        for (int mt = 0; mt < 2; mt++)
            #pragma unroll
            for (int r = 0; r < 4; r++)
                sq[mt][r] += __shfl_xor(sq[mt][r], off, 64);
    if (li == 0) {
        #pragma unroll
        for (int mt = 0; mt < 2; mt++)
            #pragma unroll
            for (int r = 0; r < 4; r++)
                redq[(mt * 16 + quad * 4 + r) * 4 + wv] = sq[mt][r];
    }
    __syncthreads();
    #pragma unroll
    for (int mt = 0; mt < 2; mt++)
        #pragma unroll
        for (int r = 0; r < 4; r++) {
            int rowm = mt * 16 + quad * 4 + r;
            float tot = redq[rowm * 4 + 0] + redq[rowm * 4 + 1] +
                        redq[rowm * 4 + 2] + redq[rowm * 4 + 3];
            float inv = 1.f / (sqrtf(tot) + 1e-4f);
            #pragma unroll
            for (int nt = 0; nt < 4; nt++) {
                float v = acc2[mt][nt][r] * inv;
                unsigned short h, l;
                split_hl(v, h, l);
                int col = n0w + nt * 16 + li;
                emh[rowm * 264 + col] = h;
                eml[rowm * 264 + col] = l;
            }
        }
    __syncthreads();

    // phase D: scores = embed @ zn^T (wave covers 128 z's, 2 m-tiles)
    f32x4 acc3[2][8];
    #pragma unroll
    for (int i = 0; i < 2; i++)
        #pragma unroll
        for (int j = 0; j < 8; j++) acc3[i][j] = zz;
    int zn0 = wv * 128;
    #pragma unroll
    for (int ks = 0; ks < 8; ks++) {
        int ko = ks * 32 + quad * 8;
        bf16x8 ah0 = *(const bf16x8*)&emh[li * 264 + ko];
        bf16x8 al0 = *(const bf16x8*)&eml[li * 264 + ko];
        bf16x8 ah1 = *(const bf16x8*)&emh[(16 + li) * 264 + ko];
        bf16x8 al1 = *(const bf16x8*)&eml[(16 + li) * 264 + ko];
        #pragma unroll
        for (int nt = 0; nt < 8; nt++) {
            size_t zo = (size_t)(zn0 + nt * 16 + li) * EDIM + ko;
            bf16x8 bh = *(const bf16x8*)(znh + zo);
            bf16x8 bl = *(const bf16x8*)(znl + zo);
            acc3[0][nt] = __builtin_amdgcn_mfma_f32_16x16x32_bf16(ah0, bh, acc3[0][nt], 0, 0, 0);
            acc3[0][nt] = __builtin_amdgcn_mfma_f32_16x16x32_bf16(ah0, bl, acc3[0][nt], 0, 0, 0);
            acc3[0][nt] = __builtin_amdgcn_mfma_f32_16x16x32_bf16(al0, bh, acc3[0][nt], 0, 0, 0);
            acc3[1][nt] = __builtin_amdgcn_mfma_f32_16x16x32_bf16(ah1, bh, acc3[1][nt], 0, 0, 0);
            acc3[1][nt] = __builtin_amdgcn_mfma_f32_16x16x32_bf16(ah1, bl, acc3[1][nt], 0, 0, 0);
            acc3[1][nt] = __builtin_amdgcn_mfma_f32_16x16x32_bf16(al1, bh, acc3[1][nt], 0, 0, 0);
        }
    }

    // phase E
    if (phi == 0) {
        #pragma unroll
        for (int mt = 0; mt < 2; mt++)
            #pragma unroll
            for (int nt = 0; nt < 8; nt++)
                #pragma unroll
                for (int r = 0; r < 4; r++)
                    Cm[(size_t)(b0 + mt * 16 + quad * 4 + r) * NZV + zn0 + nt * 16 + li] =
                        acc3[mt][nt][r];
    } else {
        float bestr[2][4] = {{-3.0e38f, -3.0e38f, -3.0e38f, -3.0e38f},
                             {-3.0e38f, -3.0e38f, -3.0e38f, -3.0e38f}};
        int bnr[2][4] = {{0, 0, 0, 0}, {0, 0, 0, 0}};
        // ascending-n scan with strict > keeps the lowest index on ties
        #pragma unroll
        for (int nt = 0; nt < 8; nt++) {
            int n = zn0 + nt * 16 + li;
            #pragma unroll
            for (int mt = 0; mt < 2; mt++)
                #pragma unroll
                for (int r = 0; r < 4; r++) {
                    float v = acc3[mt][nt][r];
                    if (v > bestr[mt][r]) { bestr[mt][r] = v; bnr[mt][r] = n; }
                }
        }
        #pragma unroll
        for (int mt = 0; mt < 2; mt++)
            #pragma unroll
            for (int r = 0; r < 4; r++) {
                float bv = bestr[mt][r]; int nv = bnr[mt][r];
                #pragma unroll
                for (int off = 1; off < 16; off <<= 1) {
                    float ov = __shfl_xor(bv, off, 64);
                    int   on = __shfl_xor(nv, off, 64);
                    if (ov > bv || (ov == bv && on < nv)) { bv = ov; nv = on; }
                }
                if (li == 0) {
                    int rowm = mt * 16 + quad * 4 + r;
                    argv[rowm * 4 + wv] = bv;
                    argn[rowm * 4 + wv] = nv;
                }
            }
        __syncthreads();
        if (tid < 32) {
            float bv = argv[tid * 4]; int nv = argn[tid * 4];
            #pragma unroll
            for (int w = 1; w < 4; w++) {
                float v = argv[tid * 4 + w]; int n = argn[tid * 4 + w];
                if (v > bv || (v == bv && n < nv)) { bv = v; nv = n; }
            }
            idxout[b0 + tid] = nv;
        }
    }
}

// ---- output: out[i][j] = exp(scale) * G0[i][idx[j]] -----------------------
__global__ __launch_bounds__(256) void k_out(const float* __restrict__ C,
                                             const int* __restrict__ idx,
                                             const float* __restrict__ scale,
                                             float* __restrict__ out) {
    __shared__ float g[8][NZV];
    __shared__ int   id[2048];
    int i0 = blockIdx.y * 8;
    int j0 = blockIdx.x * 2048;
    float esc = expf(scale[0]);
    for (int u = threadIdx.x; u < 2048; u += 256) id[u] = idx[j0 + u];
    for (int u = threadIdx.x; u < 8 * NZV; u += 256) {
        int r = u >> 9, c = u & 511;
        g[r][c] = C[(size_t)(i0 + r) * NZV + c];
    }
    __syncthreads();
    int jb = threadIdx.x * 8;
    int myid[8];
    #pragma unroll
    for (int u = 0; u < 8; u++) myid[u] = id[jb + u];
    #pragma unroll
    for (int r = 0; r < 8; r++) {
        float4 o0, o1;
        o0.x = esc * g[r][myid[0]]; o0.y = esc * g[r][myid[1]];
        o0.z = esc * g[r][myid[2]]; o0.w = esc * g[r][myid[3]];
        o1.x = esc * g[r][myid[4]]; o1.y = esc * g[r][myid[5]];
        o1.z = esc * g[r][myid[6]]; o1.w = esc * g[r][myid[7]];
        float4* dst = (float4*)(out + (size_t)(i0 + r) * NB + j0 + jb);
        dst[0] = o0; dst[1] = o1;
    }
}

extern "C" void kernel_launch(void* const* d_in, const int* in_sizes, int n_in,
                              void* d_out, int out_size, void* d_ws, size_t ws_size,
                              hipStream_t stream) {
    const int*   s     = (const int*)d_in[0];
    const int*   sp    = (const int*)d_in[1];
    const float* tab   = (const float*)d_in[2];
    const float* wE    = (const float*)d_in[3];
    const float* bE    = (const float*)d_in[4];
    const float* w1a   = (const float*)d_in[5];
    const float* b1a   = (const float*)d_in[6];
    const float* w2a   = (const float*)d_in[7];
    const float* b2a   = (const float*)d_in[8];
    const float* lwa   = (const float*)d_in[9];
    const float* lba   = (const float*)d_in[10];
    const float* w1b   = (const float*)d_in[11];
    const float* b1b   = (const float*)d_in[12];
    const float* w2b   = (const float*)d_in[13];
    const float* b2b   = (const float*)d_in[14];
    const float* lwb   = (const float*)d_in[15];
    const float* lbb   = (const float*)d_in[16];
    const float* zv    = (const float*)d_in[17];
    const float* scale = (const float*)d_in[18];

    float* out = (float*)d_out;
    float* wsf = (float*)d_ws;

    // d_ws layout (float units), ~20.1 MB total
    float* tn   = wsf;                                        // [0, 448)
    float* Aw   = wsf + 448;                                  // [448, 8512)
    float* beff = wsf + 8512;                                 // [8512, 9312)
    int*   idx  = (int*)(wsf + 9312);                         // [9312, 17504)
    float* T    = wsf + 17504;                                // [17504, 297504)
    float* Cm   = wsf + 297504;                               // 8192*512 -> [.., 4491808)
    unsigned short* wh  = (unsigned short*)(wsf + 4491808);   // 409600 u16
    unsigned short* wl  = (unsigned short*)(wsf + 4696608);
    unsigned short* znh = (unsigned short*)(wsf + 4901408);   // 131072 u16
    unsigned short* znl = (unsigned short*)(wsf + 4966944);   // ends 5032480

    // d_out as scratch for a2 (dead before k_out overwrites):
    // a2h/a2l each [2][8192][800] u16 = 13,107,200 u16 = 6,553,600 floats
    unsigned short* a2h = (unsigned short*)out;
    unsigned short* a2l = (unsigned short*)(out + 6553600);

    k_norm_embed<<<DICT, 64, 0, stream>>>(tab, tn);
    k_prep_zw<<<NZV + 1600, 256, 0, stream>>>(zv, lwa, lwb, znh, znl, wh, wl);
    k_prep_ab<<<34, 256, 0, stream>>>(wE, tn, w1a, b1a, w1b, b1b, bE, Aw, beff);
    k_build_T<<<dim3(25 * DICT, 2), 256, 0, stream>>>(w1a, w1b, Aw, T);
    k_gcv<<<dim3(NB / 16, 2), 256, 0, stream>>>(s, sp, T, beff, w2a, b2a, w2b, b2b,
                                                a2h, a2l);
    k_emb<<<dim3(NB / 32, 2), 256, 0, stream>>>(a2h, a2l, wh, wl, lba, lbb,
                                                znh, znl, Cm, idx);
    k_out<<<dim3(NB / 2048, NB / 8), 256, 0, stream>>>(Cm, idx, scale, out);
}